// Round 8
// baseline (26.749 us; speedup 1.0000x reference)
//
#include <hip/hip_runtime.h>
#include <hip/hip_fp16.h>
#include <hip/hip_bf16.h>

#define OUTF 11008
#define INF  4096

typedef unsigned int uint;
typedef __attribute__((ext_vector_type(8))) _Float16 f16x8;  // MFMA A/B (4 VGPR)
typedef __attribute__((ext_vector_type(4))) float f32x4;     // MFMA C/D

typedef __attribute__((address_space(1))) void gvoid_t;
typedef __attribute__((address_space(3))) void svoid_t;

union UA { uint4 u4; uint u[4]; f16x8 v; };
union UH { uint u; __half2 h; };
union USH { unsigned short s; __half h; };

#define WAITV(n) asm volatile("s_waitcnt vmcnt(" #n ")" ::: "memory")
#define FENCE()  asm volatile("" ::: "memory")   // compiler-order pin (0 instructions)

// ---- pre-pack x (f32 16x4096) -> f16 MFMA A-fragments.
// xpk[kblk*64+l] : lane l (col=l&15,q=l>>4) holds x[col][kblk*32+q*8 .. +8] as 8 f16
__global__ __launch_bounds__(256) void pack_x_kernel(const float* __restrict__ x,
                                                     uint4* __restrict__ xpk) {
  const int t = (int)blockIdx.x * 256 + (int)threadIdx.x;   // 0..8191
  const int kblk = t >> 6, l = t & 63, col = l & 15, q = l >> 4;
  const float* src = x + (size_t)col * INF + kblk * 32 + q * 8;
  const float4 a = *(const float4*)src;
  const float4 b = *(const float4*)(src + 4);
  UH c0, c1, c2, c3;
  c0.h = __floats2half2_rn(a.x, a.y);
  c1.h = __floats2half2_rn(a.z, a.w);
  c2.h = __floats2half2_rn(b.x, b.y);
  c3.h = __floats2half2_rn(b.z, b.w);
  xpk[t] = make_uint4(c0.u, c1.u, c2.u, c3.u);
}

// One wave (64 thr) owns one 16-row o-tile, full K. No barriers anywhere.
__global__ __launch_bounds__(64) void lin2bit_kernel(
    const uint4* __restrict__ xpk, const int* __restrict__ wq,
    const float* __restrict__ wn, const float* __restrict__ bias,
    float* __restrict__ out)
{
  // [0,2048) LUT | [2048,10240) norms 8KB | [10240,18432) W0 | [18432,26624) W1
  __shared__ __align__(16) char lds[26624];
  char* LUT = lds;
  char* NL  = lds + 2048;
  char* W0  = lds + 10240;
  char* W1  = lds + 18432;

  const int l   = threadIdx.x;
  const int col = l & 15;            // A-row (m) / B-col (o) / D-col
  const int q   = l >> 4;            // lane covers k = 8q..8q+7 of each group
  const int o0  = (int)blockIdx.x << 4;

  // per-lane DMA geometry: instr i covers rows {2i, 2i+1}, 512 B each, contiguous.
  // LDS layout (linear dst): [r][s][b] = r*512 + s*32 + b, swizzled content:
  // LDS granule at (r, w) holds global bytes (r, w ^ ((r&7)<<4)).
  const int  dr   = l >> 5;               // row parity within instr
  const int  dw   = (l & 31) << 4;        // within-row byte (granule)
  char*      dst0 = (char*)nullptr;       // computed per use

  // ---- bias first (retires first; keeps vmcnt counts clean)
  const float bval = bias[o0 + col];
  FENCE();

  // ---- norms DMA: 8 KB contiguous tile slab (once per tile)
  {
    const char* wnb = (const char*)wn;
#pragma unroll
    for (int i = 0; i < 8; ++i) {
      const int r = 2 * i + dr;
      const char* src = wnb + (size_t)(o0 + r) * 512 + (dw ^ ((r & 7) << 4));
      __builtin_amdgcn_global_load_lds((gvoid_t*)src,
                                       (svoid_t*)(NL + i * 1024 + l * 16), 16, 0, 0);
    }
  }
  FENCE();

  const char* wqb = (const char*)wq;
#define STAGE_W(c, buf) { \
    _Pragma("unroll") \
    for (int i = 0; i < 8; ++i) { \
      const int r = 2 * i + dr; \
      const char* src = wqb + (size_t)(o0 + r) * 4096 + (c) * 512 + (dw ^ ((r & 7) << 4)); \
      __builtin_amdgcn_global_load_lds((gvoid_t*)src, \
                                       (svoid_t*)((buf) + i * 1024 + l * 16), 16, 0, 0); \
    } }

  STAGE_W(0, W0);
  FENCE();

  // ---- A fragments for chunk 0
  UA af[16];
#pragma unroll
  for (int j = 0; j < 16; ++j) af[j].u4 = xpk[j * 64 + l];
  FENCE();

  STAGE_W(1, W1);
  FENCE();

  // ---- LUT build on VALU while DMAs fly: entry e = 4 f16 levels of byte e
  {
    USH h0, h1, h2, h3;
    h0.h = __float2half(-1.0f);  h1.h = __float2half(-0.333f);
    h2.h = __float2half(0.333f); h3.h = __float2half(1.0f);
    const uint hv[4] = {h0.s, h1.s, h2.s, h3.s};
#pragma unroll
    for (int e = 0; e < 4; ++e) {
      const int idx = e * 64 + l;
      const uint lo = hv[idx & 3]        | (hv[(idx >> 2) & 3] << 16);
      const uint hi = hv[(idx >> 4) & 3] | (hv[(idx >> 6) & 3] << 16);
      *(uint2*)(LUT + idx * 8) = make_uint2(lo, hi);
    }
  }

  f32x4 acc = {0.f, 0.f, 0.f, 0.f};
  const int swz = (col & 7) << 4;
  const int Vw  = (col * 512 + q * 8) ^ swz;   // weight read base (XOR j*32 per step)

#pragma unroll
  for (int c = 0; c < 8; ++c) {
    // entry: need weights(c) + af(c); allow next-chunk DMA (8) to stay in flight
    if (c < 7) { WAITV(8); } else { WAITV(0); }

    // norms for chunk c: 4 x b128 from swizzled NL
    __half2 nv2[16];
#pragma unroll
    for (int jj = 0; jj < 4; ++jj) {
      const float4 v = *(const float4*)(NL + ((col * 512 + c * 64 + jj * 16) ^ swz));
      nv2[jj * 4 + 0] = __floats2half2_rn(v.x, v.x);
      nv2[jj * 4 + 1] = __floats2half2_rn(v.y, v.y);
      nv2[jj * 4 + 2] = __floats2half2_rn(v.z, v.z);
      nv2[jj * 4 + 3] = __floats2half2_rn(v.w, v.w);
    }

    const char* wb = (c & 1) ? W1 : W0;
#pragma unroll
    for (int j = 0; j < 16; ++j) {
      const uint2 p  = *(const uint2*)(wb + (Vw ^ (j * 32)));
      const uint2 e0 = *(const uint2*)(LUT + ((size_t)(uint)p.x << 3));
      const uint2 e1 = *(const uint2*)(LUT + ((size_t)(uint)p.y << 3));
      UH a0, a1, a2, a3, b0, b1, b2, b3;
      a0.u = e0.x; a1.u = e0.y; a2.u = e1.x; a3.u = e1.y;
      b0.h = __hmul2(a0.h, nv2[j]); b1.h = __hmul2(a1.h, nv2[j]);
      b2.h = __hmul2(a2.h, nv2[j]); b3.h = __hmul2(a3.h, nv2[j]);
      UA B; B.u[0] = b0.u; B.u[1] = b1.u; B.u[2] = b2.u; B.u[3] = b3.u;
      acc = __builtin_amdgcn_mfma_f32_16x16x32_f16(af[j].v, B.v, acc, 0, 0, 0);
    }

    // issue next-chunk streams AFTER this chunk's reads (order is load-bearing)
    if (c < 7) {
      FENCE();
#pragma unroll
      for (int j = 0; j < 16; ++j) af[j].u4 = xpk[((c + 1) * 16 + j) * 64 + l];
      FENCE();
      if (c < 6) {
        char* nb = (c & 1) ? W1 : W0;        // buffer just consumed
        STAGE_W(c + 2, nb);
      }
      FENCE();
    }
  }
#undef STAGE_W

  // ---- store: D row = q*4 + i, col = col (no reduction needed)
#pragma unroll
  for (int i = 0; i < 4; ++i)
    out[(size_t)(q * 4 + i) * OUTF + o0 + col] = acc[i] + bval;
}

extern "C" void kernel_launch(void* const* d_in, const int* in_sizes, int n_in,
                              void* d_out, int out_size, void* d_ws, size_t ws_size,
                              hipStream_t stream) {
  (void)in_sizes; (void)n_in; (void)out_size; (void)ws_size;
  const float* x    = (const float*)d_in[0];
  const int*   wq   = (const int*)d_in[1];
  const float* wn   = (const float*)d_in[2];
  const float* bias = (const float*)d_in[3];
  float*       out  = (float*)d_out;
  uint4*       xpk  = (uint4*)d_ws;   // 128 KB workspace
  pack_x_kernel<<<dim3(32), dim3(256), 0, stream>>>(x, xpk);
  lin2bit_kernel<<<dim3(OUTF / 16), dim3(64), 0, stream>>>(xpk, wq, wn, bias, out);
}

// Round 9
// 21.608 us; speedup vs baseline: 1.2379x; 1.2379x over previous
//
#include <hip/hip_runtime.h>
#include <hip/hip_fp16.h>

#define OUTF 11008
#define INF  4096

typedef unsigned int uint;
typedef __attribute__((ext_vector_type(8))) _Float16 f16x8;  // MFMA A/B (4 VGPR)
typedef __attribute__((ext_vector_type(4))) float f32x4;     // MFMA C/D

typedef __attribute__((address_space(1))) void gvoid_t;
typedef __attribute__((address_space(3))) void svoid_t;

union UA { uint4 u4; uint u[4]; f16x8 v; };
union UH { uint u; __half2 h; };
union USH { unsigned short s; __half h; };

#define WAITV(n) asm volatile("s_waitcnt vmcnt(" #n ")" ::: "memory")
#define FENCE()  asm volatile("" ::: "memory")   // compiler-order pin

// ---- pre-pack x (f32 16x4096) -> f16 MFMA A-fragments.
// xpk[kblk*64+l] : lane l (col=l&15,q=l>>4) holds x[col][kblk*32+q*8 .. +8] as 8 f16
__global__ __launch_bounds__(256) void pack_x_kernel(const float* __restrict__ x,
                                                     uint4* __restrict__ xpk) {
  const int t = (int)blockIdx.x * 256 + (int)threadIdx.x;   // 0..8191
  const int kblk = t >> 6, l = t & 63, col = l & 15, q = l >> 4;
  const float* src = x + (size_t)col * INF + kblk * 32 + q * 8;
  const float4 a = *(const float4*)src;
  const float4 b = *(const float4*)(src + 4);
  UH c0, c1, c2, c3;
  c0.h = __floats2half2_rn(a.x, a.y);
  c1.h = __floats2half2_rn(a.z, a.w);
  c2.h = __floats2half2_rn(b.x, b.y);
  c3.h = __floats2half2_rn(b.z, b.w);
  xpk[t] = make_uint4(c0.u, c1.u, c2.u, c3.u);
}

// Block = 256 thr = 4 waves; one 16-row o-tile; wave wv owns K-quarter wv.
// Waves run barrier-free pipelines; single LDS reduction at the end.
__global__ __launch_bounds__(256, 3) void lin2bit_kernel(
    const uint4* __restrict__ xpk, const int* __restrict__ wq,
    const float* __restrict__ wn, const float* __restrict__ bias,
    float* __restrict__ out)
{
  // [0,2048) LUT | [2048,10240) norms: wv*2048, 2KB each | [10240,43008) W: wv*8192
  __shared__ __align__(16) char lds[43008];
  char* LUT = lds;

  const int tid = threadIdx.x;
  const int wv  = tid >> 6;
  const int l   = tid & 63;
  const int col = l & 15;            // A-row (m) / B-col (o)
  const int q   = l >> 4;            // lane covers k = 8q..8q+7 of each group
  const int o0  = (int)blockIdx.x << 4;

  char* NL = lds + 2048 + wv * 2048;         // norms: [r][128B], granule-swizzled
  char* W0 = lds + 10240 + wv * 8192;        // chunk slab A: [r][256B], swizzled
  char* W1 = W0 + 4096;                      // chunk slab B

  const char* wqb = (const char*)wq;
  const char* wnb = (const char*)wn;

  // ---- norms DMA: 2 instr, 8 rows each, 16B/lane, source-side XOR swizzle
  {
    const int r7 = l >> 3;                   // = r&7 for both instrs
    const char* s0 = wnb + (size_t)(o0 + r7) * 512 + wv * 128 + (((l & 7) ^ r7) << 4);
#pragma unroll
    for (int i = 0; i < 2; ++i)
      __builtin_amdgcn_global_load_lds((gvoid_t*)(s0 + (size_t)i * 8 * 512),
                                       (svoid_t*)(NL + i * 1024 + l * 16), 16, 0, 0);
  }
  FENCE();

  // chunk = 8 K-groups = 16 rows x 256B. DMA: 4 instr, 4 rows each.
#define STAGE_W(c, buf) { \
    _Pragma("unroll") \
    for (int i = 0; i < 4; ++i) { \
      const int r = 4 * i + (l >> 4); \
      const char* src = wqb + (size_t)(o0 + r) * 4096 + wv * 1024 + (c) * 256 \
                        + (((l & 15) ^ (r & 7)) << 4); \
      __builtin_amdgcn_global_load_lds((gvoid_t*)src, \
                                       (svoid_t*)((buf) + i * 1024 + l * 16), 16, 0, 0); \
    } }

#define LOAD_AF(buf, c) { \
    _Pragma("unroll") \
    for (int j = 0; j < 8; ++j) \
      (buf)[j].u4 = xpk[(size_t)(wv * 32 + (c) * 8 + j) * 64 + l]; }

  UA afA[8], afB[8];
  STAGE_W(0, W0);  FENCE();
  LOAD_AF(afA, 0); FENCE();
  STAGE_W(1, W1);  FENCE();
  LOAD_AF(afB, 1); FENCE();
  // outstanding: 2 + 4 + 8 + 4 + 8 = 26

  // ---- LUT build on VALU while 26 VMEM in flight (each wave writes full LUT;
  // benign duplicate writes of identical values -> no barrier needed)
  {
    USH h0, h1, h2, h3;
    h0.h = __float2half(-1.0f);  h1.h = __float2half(-0.333f);
    h2.h = __float2half(0.333f); h3.h = __float2half(1.0f);
    const uint hv[4] = {h0.s, h1.s, h2.s, h3.s};
#pragma unroll
    for (int e = 0; e < 4; ++e) {
      const int idx = e * 64 + l;
      const uint lo = hv[idx & 3]        | (hv[(idx >> 2) & 3] << 16);
      const uint hi = hv[(idx >> 4) & 3] | (hv[(idx >> 6) & 3] << 16);
      *(uint2*)(LUT + idx * 8) = make_uint2(lo, hi);
    }
  }

  f32x4 acc = {0.f, 0.f, 0.f, 0.f};
  const int cs7 = col & 7;
  const int qh  = q >> 1;
  const int ql8 = (q & 1) * 8;

#define CHUNK(wb, af, c) { \
    const float4 n0 = *(const float4*)(NL + col * 128 + (((2 * (c))     ^ cs7) << 4)); \
    const float4 n1 = *(const float4*)(NL + col * 128 + (((2 * (c) + 1) ^ cs7) << 4)); \
    __half2 nv2[8]; \
    nv2[0] = __floats2half2_rn(n0.x, n0.x); nv2[1] = __floats2half2_rn(n0.y, n0.y); \
    nv2[2] = __floats2half2_rn(n0.z, n0.z); nv2[3] = __floats2half2_rn(n0.w, n0.w); \
    nv2[4] = __floats2half2_rn(n1.x, n1.x); nv2[5] = __floats2half2_rn(n1.y, n1.y); \
    nv2[6] = __floats2half2_rn(n1.z, n1.z); nv2[7] = __floats2half2_rn(n1.w, n1.w); \
    _Pragma("unroll") \
    for (int j = 0; j < 8; ++j) { \
      const uint2 p  = *(const uint2*)((wb) + col * 256 + (((2 * j + qh) ^ cs7) << 4) + ql8); \
      const uint2 e0 = *(const uint2*)(LUT + ((size_t)(uint)p.x << 3)); \
      const uint2 e1 = *(const uint2*)(LUT + ((size_t)(uint)p.y << 3)); \
      UH a0, a1, a2, a3, b0, b1, b2, b3; \
      a0.u = e0.x; a1.u = e0.y; a2.u = e1.x; a3.u = e1.y; \
      b0.h = __hmul2(a0.h, nv2[j]); b1.h = __hmul2(a1.h, nv2[j]); \
      b2.h = __hmul2(a2.h, nv2[j]); b3.h = __hmul2(a3.h, nv2[j]); \
      UA B; B.u[0] = b0.u; B.u[1] = b1.u; B.u[2] = b2.u; B.u[3] = b3.u; \
      acc = __builtin_amdgcn_mfma_f32_16x16x32_f16((af)[j].v, B.v, acc, 0, 0, 0); \
    } }

  // ladder: every wait targets loads issued a full chunk earlier
  WAITV(12); CHUNK(W0, afA, 0)
  FENCE();   STAGE_W(2, W0);  FENCE();  LOAD_AF(afA, 2);  FENCE();
  WAITV(12); CHUNK(W1, afB, 1)
  FENCE();   STAGE_W(3, W1);  FENCE();  LOAD_AF(afB, 3);  FENCE();
  WAITV(12); CHUNK(W0, afA, 2)
  WAITV(0);  CHUNK(W1, afB, 3)
#undef CHUNK
#undef STAGE_W
#undef LOAD_AF

  // ---- cross-wave K reduction (overlay on LUT region) + bias + store
  __syncthreads();
  float* red = (float*)lds;          // 1024 floats = 4 KB
  red[wv * 256 +   0 + l] = acc[0];
  red[wv * 256 +  64 + l] = acc[1];
  red[wv * 256 + 128 + l] = acc[2];
  red[wv * 256 + 192 + l] = acc[3];
  __syncthreads();
  const int t = tid;
  const float s = red[t] + red[256 + t] + red[512 + t] + red[768 + t];
  const int m  = ((t & 63) >> 4) * 4 + (t >> 6);   // D row = q*4 + reg
  const int oc = t & 15;                            // D col
  out[(size_t)m * OUTF + o0 + oc] = s + bias[o0 + oc];
}

extern "C" void kernel_launch(void* const* d_in, const int* in_sizes, int n_in,
                              void* d_out, int out_size, void* d_ws, size_t ws_size,
                              hipStream_t stream) {
  (void)in_sizes; (void)n_in; (void)out_size; (void)ws_size;
  const float* x    = (const float*)d_in[0];
  const int*   wq   = (const int*)d_in[1];
  const float* wn   = (const float*)d_in[2];
  const float* bias = (const float*)d_in[3];
  float*       out  = (float*)d_out;
  uint4*       xpk  = (uint4*)d_ws;   // 128 KB workspace
  pack_x_kernel<<<dim3(32), dim3(256), 0, stream>>>(x, xpk);
  lin2bit_kernel<<<dim3(OUTF / 16), dim3(256), 0, stream>>>(xpk, wq, wn, bias, out);
}